// Round 3
// baseline (20289.255 us; speedup 1.0000x reference)
//
#include <hip/hip_runtime.h>

typedef short  sh8  __attribute__((ext_vector_type(8)));
typedef float  f32x4 __attribute__((ext_vector_type(4)));
typedef ushort ush4 __attribute__((ext_vector_type(4)));

#define TS 1024
#define BB 64
#define HH 512

// d_out element offsets (fp32 elements): output [1024][64][1024], h [2][64][1024], c [2][64][1024]
#define HOFF 67108864ull
#define HC_DELTA 131072ull

// barrier area: unsigned bar[2][1056] per-pipeline per-slot counters + abort at [2112]
#define BAR_WORDS 2120

static __device__ __forceinline__ float sigm(float x){ return 1.f/(1.f+__expf(-x)); }
static __device__ __forceinline__ float tanh_(float x){ return 1.f - 2.f/(__expf(2.f*x)+1.f); }
static __device__ __forceinline__ ushort f2bf(float f){
  unsigned u = __float_as_uint(f);
  u += 0x7fffu + ((u>>16)&1u);   // RNE
  return (ushort)(u>>16);
}

// coherent (agent-scope, cache-bypassing, NO cache maintenance) helpers
static __device__ __forceinline__ sh8 ldh8(const ushort* p){
  union { unsigned long long u[2]; sh8 v; } r;
  r.u[0] = __hip_atomic_load((const unsigned long long*)p,     __ATOMIC_RELAXED, __HIP_MEMORY_SCOPE_AGENT);
  r.u[1] = __hip_atomic_load((const unsigned long long*)(p+4), __ATOMIC_RELAXED, __HIP_MEMORY_SCOPE_AGENT);
  return r.v;
}
static __device__ __forceinline__ void sth4(ushort* p, unsigned v){
  __hip_atomic_store((unsigned*)p, v, __ATOMIC_RELAXED, __HIP_MEMORY_SCOPE_AGENT);
}

// ---- prep: fp32 -> bf16 conversions into ws (also zeroes barrier state) ----
__global__ __launch_bounds__(256) void cvt_w(
    const float* __restrict__ p0, const float* __restrict__ p1,
    const float* __restrict__ p2, const float* __restrict__ p3,
    const float* __restrict__ p4, const float* __restrict__ p5,
    const float* __restrict__ p6, const float* __restrict__ p7,
    ushort* __restrict__ wb, unsigned* __restrict__ bar)
{
  if (blockIdx.x == 0){
    for (unsigned i = threadIdx.x; i < BAR_WORDS; i += 256) bar[i] = 0u;
  }
  const unsigned gid = blockIdx.x*256 + threadIdx.x;   // 2^21 float4s total
  const unsigned m = gid >> 18;                        // matrix index 0..7
  const unsigned o = gid & 0x3FFFFu;                   // float4 offset in matrix
  const float* src;
  switch(m){
    case 0: src=p0; break; case 1: src=p1; break; case 2: src=p2; break; case 3: src=p3; break;
    case 4: src=p4; break; case 5: src=p5; break; case 6: src=p6; break; default: src=p7; break;
  }
  float4 f = *(const float4*)(src + (size_t)o*4);
  ush4 r; r.x=f2bf(f.x); r.y=f2bf(f.y); r.z=f2bf(f.z); r.w=f2bf(f.w);
  *(ush4*)(wb + ((size_t)m<<20) + (size_t)o*4) = r;
}

__global__ __launch_bounds__(256) void cvt_x(
    const float* __restrict__ x, ushort* __restrict__ xb)
{
  const unsigned gid = blockIdx.x*256 + threadIdx.x;   // 2^23 float4s
  float4 f = *(const float4*)(x + (size_t)gid*4);
  ush4 r; r.x=f2bf(f.x); r.y=f2bf(f.y); r.z=f2bf(f.z); r.w=f2bf(f.w);
  *(ush4*)(xb + (size_t)gid*4) = r;
}

static __device__ __forceinline__ sh8 ld_cvt8(const float* p){
  float4 f0 = *(const float4*)p;
  float4 f1 = *(const float4*)(p+4);
  sh8 r;
  r[0]=(short)f2bf(f0.x); r[1]=(short)f2bf(f0.y); r[2]=(short)f2bf(f0.z); r[3]=(short)f2bf(f0.w);
  r[4]=(short)f2bf(f1.x); r[5]=(short)f2bf(f1.y); r[6]=(short)f2bf(f1.z); r[7]=(short)f2bf(f1.w);
  return r;
}

// 128-block barrier with ZERO cache maintenance in steady state:
//  - arrival: relaxed agent fetch_add (h stores already at coherence point:
//    __syncthreads drained each wave's vmcnt, and h stores are sc-flagged)
//  - spin: relaxed agent loads (sc-bypass, always fresh), bounded for safety
static __device__ __forceinline__ void pipe_barrier(unsigned* ctr, unsigned* abortf)
{
  __syncthreads();                       // drains vmcnt for ALL waves (h stores visible)
  asm volatile("" ::: "memory");
  if (threadIdx.x == 0){
    if (__hip_atomic_load(abortf, __ATOMIC_RELAXED, __HIP_MEMORY_SCOPE_AGENT) == 0u){
      __hip_atomic_fetch_add(ctr, 1u, __ATOMIC_RELAXED, __HIP_MEMORY_SCOPE_AGENT);
      unsigned spins = 0;
      while (__hip_atomic_load(ctr, __ATOMIC_RELAXED, __HIP_MEMORY_SCOPE_AGENT) < 128u){
        __builtin_amdgcn_s_sleep(1);
        if (++spins > (1u<<19)){         // ~0.5 s worst case: bail, never hang
          __hip_atomic_store(abortf, 1u, __ATOMIC_RELAXED, __HIP_MEMORY_SCOPE_AGENT);
          break;
        }
      }
    }
  }
  asm volatile("" ::: "memory");
  __syncthreads();
}

// ============================================================================
// Persistent kernel: all 1025 pipeline slots in ONE plain launch.
// 256 blocks (1/CU). Two independent 128-block pipelines:
//   pipe 0: group 0 (L0 fwd) -> group 2 (L1 fwd)
//   pipe 1: group 1 (L0 bwd) -> group 3 (L1 bwd)
// h exchange: sc-coherent (cache-bypass) loads/stores; weights/x: cached.
// ============================================================================
template<bool XBF>
__global__ __launch_bounds__(256, 1) void lstm_persist(
    const float* __restrict__ xf, const ushort* __restrict__ xb,
    const ushort* __restrict__ wb,
    float* __restrict__ out, ushort* __restrict__ h_ws, unsigned* __restrict__ bar)
{
  const int group = blockIdx.x >> 6;   // 0:L0F 1:L0B 2:L1F 3:L1B
  const int w     = blockIdx.x & 63;   // owns h-cols [8w, 8w+8)
  const int lane  = threadIdx.x & 63;
  const int wv    = threadIdx.x >> 6;
  const int n     = lane & 15;
  const int q     = lane >> 4;

  unsigned* ctrbase = bar + (size_t)(group & 1) * 1056;
  unsigned* abortf  = bar + 2112;

  // wb matrix order: wihf0, whhf0, wihf1, whhf1, wihb0, whhb0, wihb1, whhb1
  int wbase;
  if      (group==0) wbase = 0;
  else if (group==1) wbase = 4;
  else if (group==2) wbase = 2;
  else               wbase = 6;
  const ushort* wih = wb + ((size_t)wbase<<20);
  const ushort* whh = wb + ((size_t)(wbase+1)<<20);

  // B rows (gate-striped): tile0 = {i,f}, tile1 = {g,o}
  const int r0 = ((n>>3)  )*512 + w*8 + (n&7);
  const int r1 = ((n>>3)+2)*512 + w*8 + (n&7);
  const int arow = wv*16 + n;
  const size_t aoff  = (size_t)arow*HH + q*8;
  const size_t b0off = (size_t)r0*HH + q*8;
  const size_t b1off = (size_t)r1*HH + q*8;

  const bool low = (n < 8);
  const int  col = w*8 + (n&7);
  float c_reg[4] = {0.f,0.f,0.f,0.f};   // register-resident cell state

  // prefetch x A-fragments for slot 0 (groups 0/1) — cached loads, read-only data
  sh8 ax[16];
  if (group < 2){
    if constexpr (XBF){
      const ushort* p = xb + ((group==0) ? (size_t)0 : (size_t)(TS-1)*(BB*HH));
#pragma unroll
      for (int kk=0;kk<16;++kk) ax[kk] = *(const sh8*)(p + aoff + (size_t)kk*32);
    } else {
      const float* p = xf + ((group==0) ? (size_t)0 : (size_t)(TS-1)*(BB*HH));
#pragma unroll
      for (int kk=0;kk<16;++kk) ax[kk] = ld_cvt8(p + aoff + (size_t)kk*32);
    }
  }

  for (int s = 0; s <= TS; ++s){
    const bool active = (group < 2) ? (s < TS) : (s > 0);
    if (active){
      const int  step   = (group < 2) ? s : (s-1);
      const bool have_h = (step > 0);
      const ushort* hsrc = h_ws + ((size_t)group*2 + ((s-1)&1))*(BB*HH);

      // A-input half for layer-1 groups: source layer's h (coherent loads)
      if (group >= 2){
        const ushort* xsb = h_ws + ((size_t)(group-2)*2 + ((s-1)&1))*(BB*HH);
#pragma unroll
        for (int kk=0;kk<16;++kk) ax[kk] = ldh8(xsb + aoff + (size_t)kk*32);
      }

      // issue recurrent-h coherent loads up front; x-MFMAs overlap their latency
      sh8 ah[16];
      if (have_h){
#pragma unroll
        for (int kk=0;kk<16;++kk) ah[kk] = ldh8(hsrc + aoff + (size_t)kk*32);
      }

      f32x4 acc0 = {0.f,0.f,0.f,0.f};
      f32x4 acc1 = {0.f,0.f,0.f,0.f};
#pragma unroll
      for (int kk=0;kk<16;++kk){
        acc0 = __builtin_amdgcn_mfma_f32_16x16x32_bf16(ax[kk], *(const sh8*)(wih + b0off + (size_t)kk*32), acc0, 0, 0, 0);
        acc1 = __builtin_amdgcn_mfma_f32_16x16x32_bf16(ax[kk], *(const sh8*)(wih + b1off + (size_t)kk*32), acc1, 0, 0, 0);
      }
      if (have_h){
#pragma unroll
        for (int kk=0;kk<16;++kk){
          acc0 = __builtin_amdgcn_mfma_f32_16x16x32_bf16(ah[kk], *(const sh8*)(whh + b0off + (size_t)kk*32), acc0, 0, 0, 0);
          acc1 = __builtin_amdgcn_mfma_f32_16x16x32_bf16(ah[kk], *(const sh8*)(whh + b1off + (size_t)kk*32), acc1, 0, 0, 0);
        }
      }

      ushort* hdst = h_ws + ((size_t)group*2 + (s&1))*(BB*HH);
#pragma unroll
      for (int r=0; r<4; ++r){
        float v0 = acc0[r], v1 = acc1[r];
        float p0 = __shfl_xor(v0, 8, 64);
        float p1 = __shfl_xor(v1, 8, 64);
        if (low){
          const int row = wv*16 + q*4 + r;              // C/D: row = 4q+reg
          const float iv=v0, fv=p0, gv=v1, ov=p1;
          float cn = sigm(fv)*c_reg[r] + sigm(iv)*tanh_(gv);
          float hn = sigm(ov)*tanh_(cn);
          c_reg[r] = cn;

          // pack 2 adjacent cols -> one 32-bit coherent store (even lanes)
          unsigned hb = (unsigned)f2bf(hn);
          unsigned ob = (unsigned)__shfl_xor((int)hb, 1, 64);
          if (!(n & 1))
            sth4(hdst + (size_t)row*HH + col, hb | (ob << 16));

          if (group == 2){                               // fwd out, t = s-1
            out[((size_t)(s-1)*BB + row)*1024 + col] = hn;
          } else if (group == 3){                        // bwd out, t = 1024-s
            out[((size_t)(TS-s)*BB + row)*1024 + 512 + col] = hn;
          }

          bool cap = false; size_t hoff = 0;
          if      (group==0 && s==TS-1){ cap=true; hoff = HOFF + (size_t)row*1024 + col; }
          else if (group==1 && s==0)   { cap=true; hoff = HOFF + (size_t)row*1024 + 512 + col; }
          else if (group==2 && s==TS)  { cap=true; hoff = HOFF + (size_t)(BB+row)*1024 + col; }
          else if (group==3 && s==1)   { cap=true; hoff = HOFF + (size_t)(BB+row)*1024 + 512 + col; }
          if (cap){
            out[hoff] = hn;
            out[hoff + HC_DELTA] = cn;
          }
        }
      }
    }

    // prefetch next-slot x (groups 0/1) — flies during the barrier spin
    if (group < 2 && (s+1) < TS){
      if constexpr (XBF){
        const ushort* p = xb + ((group==0) ? (size_t)(s+1)*(BB*HH) : (size_t)(TS-2-s)*(BB*HH));
#pragma unroll
        for (int kk=0;kk<16;++kk) ax[kk] = *(const sh8*)(p + aoff + (size_t)kk*32);
      } else {
        const float* p = xf + ((group==0) ? (size_t)(s+1)*(BB*HH) : (size_t)(TS-2-s)*(BB*HH));
#pragma unroll
        for (int kk=0;kk<16;++kk) ax[kk] = ld_cvt8(p + aoff + (size_t)kk*32);
      }
    }

    // per-slot barrier over this block's 128-block pipeline
    if (s < TS) pipe_barrier(ctrbase + s, abortf);
  }
}

extern "C" void kernel_launch(void* const* d_in, const int* in_sizes, int n_in,
                              void* d_out, int out_size, void* d_ws, size_t ws_size,
                              hipStream_t stream)
{
  const float* x = (const float*)d_in[0];
  const float* W[8];
  for (int i = 0; i < 8; ++i) W[i] = (const float*)d_in[i+1];
  float* out = (float*)d_out;

  // ws layout: bar (8.5KB, 512KB reserved) | h bf16 [4][2][64][512]
  //            | wb bf16 8x2048x512 (16MB) | xb bf16 1024x64x512 (64MB, optional)
  char* ws = (char*)d_ws;
  unsigned* bar  = (unsigned*)ws;
  ushort*   h_ws = (ushort*)(ws + 524288);
  ushort*   wb   = (ushort*)(ws + 1048576);
  ushort*   xb   = (ushort*)(ws + 1048576 + 16777216);
  const bool xbf = ws_size >= (1048576ull + 16777216ull + 67108864ull);

  cvt_w<<<dim3(8192), dim3(256), 0, stream>>>(W[0],W[1],W[2],W[3],W[4],W[5],W[6],W[7], wb, bar);
  if (xbf) cvt_x<<<dim3(32768), dim3(256), 0, stream>>>(x, xb);

  if (xbf)
    lstm_persist<true ><<<dim3(256), dim3(256), 0, stream>>>(x, xb, wb, out, h_ws, bar);
  else
    lstm_persist<false><<<dim3(256), dim3(256), 0, stream>>>(x, xb, wb, out, h_ws, bar);
}

// Round 4
// 14903.252 us; speedup vs baseline: 1.3614x; 1.3614x over previous
//
#include <hip/hip_runtime.h>

typedef short  sh8  __attribute__((ext_vector_type(8)));
typedef float  f32x4 __attribute__((ext_vector_type(4)));
typedef ushort ush4 __attribute__((ext_vector_type(4)));

#define TS 1024
#define BB 64
#define HH 512

// d_out element offsets (fp32 elements): output [1024][64][1024], h [2][64][1024], c [2][64][1024]
#define HOFF 67108864ull
#define HC_DELTA 131072ull

// barrier area: flags[2][128] (one word per block per pipe, epoch-valued) + abort at [256]
#define BAR_WORDS 272

static __device__ __forceinline__ float sigm(float x){ return 1.f/(1.f+__expf(-x)); }
static __device__ __forceinline__ float tanh_(float x){ return 1.f - 2.f/(__expf(2.f*x)+1.f); }
static __device__ __forceinline__ ushort f2bf(float f){
  unsigned u = __float_as_uint(f);
  u += 0x7fffu + ((u>>16)&1u);   // RNE
  return (ushort)(u>>16);
}

// coherent (agent-scope, cache-bypassing) helpers for h exchange
static __device__ __forceinline__ sh8 ldh8(const ushort* p){
  union { unsigned long long u[2]; sh8 v; } r;
  r.u[0] = __hip_atomic_load((const unsigned long long*)p,     __ATOMIC_RELAXED, __HIP_MEMORY_SCOPE_AGENT);
  r.u[1] = __hip_atomic_load((const unsigned long long*)(p+4), __ATOMIC_RELAXED, __HIP_MEMORY_SCOPE_AGENT);
  return r.v;
}
static __device__ __forceinline__ void sth4(ushort* p, unsigned v){
  __hip_atomic_store((unsigned*)p, v, __ATOMIC_RELAXED, __HIP_MEMORY_SCOPE_AGENT);
}

// ---- prep: fp32 -> bf16 conversions into ws (also zeroes barrier state) ----
__global__ __launch_bounds__(256) void cvt_w(
    const float* __restrict__ p0, const float* __restrict__ p1,
    const float* __restrict__ p2, const float* __restrict__ p3,
    const float* __restrict__ p4, const float* __restrict__ p5,
    const float* __restrict__ p6, const float* __restrict__ p7,
    ushort* __restrict__ wb, unsigned* __restrict__ bar)
{
  if (blockIdx.x == 0){
    for (unsigned i = threadIdx.x; i < BAR_WORDS; i += 256) bar[i] = 0u;
  }
  const unsigned gid = blockIdx.x*256 + threadIdx.x;   // 2^21 float4s total
  const unsigned m = gid >> 18;                        // matrix index 0..7
  const unsigned o = gid & 0x3FFFFu;                   // float4 offset in matrix
  const float* src;
  switch(m){
    case 0: src=p0; break; case 1: src=p1; break; case 2: src=p2; break; case 3: src=p3; break;
    case 4: src=p4; break; case 5: src=p5; break; case 6: src=p6; break; default: src=p7; break;
  }
  float4 f = *(const float4*)(src + (size_t)o*4);
  ush4 r; r.x=f2bf(f.x); r.y=f2bf(f.y); r.z=f2bf(f.z); r.w=f2bf(f.w);
  *(ush4*)(wb + ((size_t)m<<20) + (size_t)o*4) = r;
}

__global__ __launch_bounds__(256) void cvt_x(
    const float* __restrict__ x, ushort* __restrict__ xb)
{
  const unsigned gid = blockIdx.x*256 + threadIdx.x;   // 2^23 float4s
  float4 f = *(const float4*)(x + (size_t)gid*4);
  ush4 r; r.x=f2bf(f.x); r.y=f2bf(f.y); r.z=f2bf(f.z); r.w=f2bf(f.w);
  *(ush4*)(xb + (size_t)gid*4) = r;
}

static __device__ __forceinline__ sh8 ld_cvt8(const float* p){
  float4 f0 = *(const float4*)p;
  float4 f1 = *(const float4*)(p+4);
  sh8 r;
  r[0]=(short)f2bf(f0.x); r[1]=(short)f2bf(f0.y); r[2]=(short)f2bf(f0.z); r[3]=(short)f2bf(f0.w);
  r[4]=(short)f2bf(f1.x); r[5]=(short)f2bf(f1.y); r[6]=(short)f2bf(f1.z); r[7]=(short)f2bf(f1.w);
  return r;
}

// Distributed-flag 128-block barrier: NO same-address RMW contention.
//  arrival: block writes epoch to its OWN flag (parallel, no serialization)
//  poll:    wave 0 reads all 128 flags with 2 coalesced 64-lane sc loads
//  ordering: __syncthreads drains all waves' vmcnt (sc h-stores committed)
//            before the flag store issues; consumer loads after flag >= epoch
static __device__ __forceinline__ void pipe_barrier(
    unsigned* flags, int myidx, unsigned epoch, unsigned* abortf)
{
  __syncthreads();                     // all waves' h stores at coherence point
  if (threadIdx.x == 0)
    __hip_atomic_store(flags + myidx, epoch, __ATOMIC_RELAXED, __HIP_MEMORY_SCOPE_AGENT);
  if (threadIdx.x < 64){               // wave 0 polls
    const int lane = threadIdx.x;
    unsigned spins = 0;
    for (;;){
      unsigned f0 = __hip_atomic_load(flags + lane,      __ATOMIC_RELAXED, __HIP_MEMORY_SCOPE_AGENT);
      unsigned f1 = __hip_atomic_load(flags + 64 + lane, __ATOMIC_RELAXED, __HIP_MEMORY_SCOPE_AGENT);
      if (__all(f0 >= epoch && f1 >= epoch)) break;
      __builtin_amdgcn_s_sleep(2);
      if (++spins > (1u<<18)){         // bounded: never hang the container
        if (lane == 0) __hip_atomic_store(abortf, 1u, __ATOMIC_RELAXED, __HIP_MEMORY_SCOPE_AGENT);
        break;
      }
      if ((spins & 63u) == 0u &&
          __hip_atomic_load(abortf, __ATOMIC_RELAXED, __HIP_MEMORY_SCOPE_AGENT) != 0u) break;
    }
  }
  __syncthreads();
}

// ============================================================================
// Persistent kernel: all 1025 pipeline slots in ONE plain launch.
// 256 blocks (1/CU). Two independent 128-block pipelines:
//   pipe 0: group 0 (L0 fwd) -> group 2 (L1 fwd)
//   pipe 1: group 1 (L0 bwd) -> group 3 (L1 bwd)
// h exchange: sc-coherent loads/stores; weights: register-resident; x: cached.
// ============================================================================
template<bool XBF>
__global__ __launch_bounds__(256, 1) void lstm_persist(
    const float* __restrict__ xf, const ushort* __restrict__ xb,
    const ushort* __restrict__ wb,
    float* __restrict__ out, ushort* __restrict__ h_ws, unsigned* __restrict__ bar)
{
  const int group = blockIdx.x >> 6;   // 0:L0F 1:L0B 2:L1F 3:L1B
  const int w     = blockIdx.x & 63;   // owns h-cols [8w, 8w+8)
  const int lane  = threadIdx.x & 63;
  const int wv    = threadIdx.x >> 6;
  const int n     = lane & 15;
  const int q     = lane >> 4;

  unsigned* flags  = bar + (size_t)(group & 1) * 128;   // this pipe's 128 flags
  const int myidx  = ((group >> 1) & 1) * 64 + w;       // 0..63 L0, 64..127 L1
  unsigned* abortf = bar + 256;

  // wb matrix order: wihf0, whhf0, wihf1, whhf1, wihb0, whhb0, wihb1, whhb1
  int wbase;
  if      (group==0) wbase = 0;
  else if (group==1) wbase = 4;
  else if (group==2) wbase = 2;
  else               wbase = 6;
  const ushort* wih = wb + ((size_t)wbase<<20);
  const ushort* whh = wb + ((size_t)(wbase+1)<<20);

  // B rows (gate-striped): tile0 = {i,f}, tile1 = {g,o}
  const int r0 = ((n>>3)  )*512 + w*8 + (n&7);
  const int r1 = ((n>>3)+2)*512 + w*8 + (n&7);
  const int arow = wv*16 + n;
  const size_t aoff  = (size_t)arow*HH + q*8;
  const size_t b0off = (size_t)r0*HH + q*8;
  const size_t b1off = (size_t)r1*HH + q*8;

  // ---- register-resident weights (identical across the 4 waves) ----
  sh8 wi0[16], wi1[16], wh0[16], wh1[16];
#pragma unroll
  for (int kk=0; kk<16; ++kk){
    wi0[kk] = *(const sh8*)(wih + b0off + (size_t)kk*32);
    wi1[kk] = *(const sh8*)(wih + b1off + (size_t)kk*32);
    wh0[kk] = *(const sh8*)(whh + b0off + (size_t)kk*32);
    wh1[kk] = *(const sh8*)(whh + b1off + (size_t)kk*32);
  }

  const bool low = (n < 8);
  const int  col = w*8 + (n&7);
  float c_reg[4] = {0.f,0.f,0.f,0.f};   // register-resident cell state

  // prefetch x A-fragments for slot 0 (groups 0/1) — cached loads
  sh8 ax[16];
  if (group < 2){
    if constexpr (XBF){
      const ushort* p = xb + ((group==0) ? (size_t)0 : (size_t)(TS-1)*(BB*HH));
#pragma unroll
      for (int kk=0;kk<16;++kk) ax[kk] = *(const sh8*)(p + aoff + (size_t)kk*32);
    } else {
      const float* p = xf + ((group==0) ? (size_t)0 : (size_t)(TS-1)*(BB*HH));
#pragma unroll
      for (int kk=0;kk<16;++kk) ax[kk] = ld_cvt8(p + aoff + (size_t)kk*32);
    }
  }

  for (int s = 0; s <= TS; ++s){
    const bool active = (group < 2) ? (s < TS) : (s > 0);
    if (active){
      const int  step   = (group < 2) ? s : (s-1);
      const bool have_h = (step > 0);
      const ushort* hsrc = h_ws + ((size_t)group*2 + ((s-1)&1))*(BB*HH);

      // A-input half for layer-1 groups: source layer's h (coherent loads, issue first)
      if (group >= 2){
        const ushort* xsb = h_ws + ((size_t)(group-2)*2 + ((s-1)&1))*(BB*HH);
#pragma unroll
        for (int kk=0;kk<16;++kk) ax[kk] = ldh8(xsb + aoff + (size_t)kk*32);
      }

      // issue recurrent-h coherent loads up front; x-MFMAs overlap their latency
      sh8 ah[16];
      if (have_h){
#pragma unroll
        for (int kk=0;kk<16;++kk) ah[kk] = ldh8(hsrc + aoff + (size_t)kk*32);
      }

      f32x4 acc0 = {0.f,0.f,0.f,0.f};
      f32x4 acc1 = {0.f,0.f,0.f,0.f};
#pragma unroll
      for (int kk=0;kk<16;++kk){
        acc0 = __builtin_amdgcn_mfma_f32_16x16x32_bf16(ax[kk], wi0[kk], acc0, 0, 0, 0);
        acc1 = __builtin_amdgcn_mfma_f32_16x16x32_bf16(ax[kk], wi1[kk], acc1, 0, 0, 0);
      }
      if (have_h){
#pragma unroll
        for (int kk=0;kk<16;++kk){
          acc0 = __builtin_amdgcn_mfma_f32_16x16x32_bf16(ah[kk], wh0[kk], acc0, 0, 0, 0);
          acc1 = __builtin_amdgcn_mfma_f32_16x16x32_bf16(ah[kk], wh1[kk], acc1, 0, 0, 0);
        }
      }

      ushort* hdst = h_ws + ((size_t)group*2 + (s&1))*(BB*HH);
#pragma unroll
      for (int r=0; r<4; ++r){
        float v0 = acc0[r], v1 = acc1[r];
        float p0 = __shfl_xor(v0, 8, 64);
        float p1 = __shfl_xor(v1, 8, 64);
        if (low){
          const int row = wv*16 + q*4 + r;              // C/D: row = 4q+reg
          const float iv=v0, fv=p0, gv=v1, ov=p1;
          float cn = sigm(fv)*c_reg[r] + sigm(iv)*tanh_(gv);
          float hn = sigm(ov)*tanh_(cn);
          c_reg[r] = cn;

          // pack 2 adjacent cols -> one 32-bit coherent store (even lanes)
          unsigned hb = (unsigned)f2bf(hn);
          unsigned ob = (unsigned)__shfl_xor((int)hb, 1, 64);
          if (!(n & 1))
            sth4(hdst + (size_t)row*HH + col, hb | (ob << 16));

          if (group == 2){                               // fwd out, t = s-1
            out[((size_t)(s-1)*BB + row)*1024 + col] = hn;
          } else if (group == 3){                        // bwd out, t = 1024-s
            out[((size_t)(TS-s)*BB + row)*1024 + 512 + col] = hn;
          }

          bool cap = false; size_t hoff = 0;
          if      (group==0 && s==TS-1){ cap=true; hoff = HOFF + (size_t)row*1024 + col; }
          else if (group==1 && s==0)   { cap=true; hoff = HOFF + (size_t)row*1024 + 512 + col; }
          else if (group==2 && s==TS)  { cap=true; hoff = HOFF + (size_t)(BB+row)*1024 + col; }
          else if (group==3 && s==1)   { cap=true; hoff = HOFF + (size_t)(BB+row)*1024 + 512 + col; }
          if (cap){
            out[hoff] = hn;
            out[hoff + HC_DELTA] = cn;
          }
        }
      }
    }

    // prefetch next-slot x (groups 0/1) — flies during the barrier poll
    if (group < 2 && (s+1) < TS){
      if constexpr (XBF){
        const ushort* p = xb + ((group==0) ? (size_t)(s+1)*(BB*HH) : (size_t)(TS-2-s)*(BB*HH));
#pragma unroll
        for (int kk=0;kk<16;++kk) ax[kk] = *(const sh8*)(p + aoff + (size_t)kk*32);
      } else {
        const float* p = xf + ((group==0) ? (size_t)(s+1)*(BB*HH) : (size_t)(TS-2-s)*(BB*HH));
#pragma unroll
        for (int kk=0;kk<16;++kk) ax[kk] = ld_cvt8(p + aoff + (size_t)kk*32);
      }
    }

    // per-slot barrier over this block's 128-block pipeline
    if (s < TS) pipe_barrier(flags, myidx, (unsigned)(s+1), abortf);
  }
}

extern "C" void kernel_launch(void* const* d_in, const int* in_sizes, int n_in,
                              void* d_out, int out_size, void* d_ws, size_t ws_size,
                              hipStream_t stream)
{
  const float* x = (const float*)d_in[0];
  const float* W[8];
  for (int i = 0; i < 8; ++i) W[i] = (const float*)d_in[i+1];
  float* out = (float*)d_out;

  // ws layout: bar (1KB used, 512KB reserved) | h bf16 [4][2][64][512]
  //            | wb bf16 8x2048x512 (16MB) | xb bf16 1024x64x512 (64MB, optional)
  char* ws = (char*)d_ws;
  unsigned* bar  = (unsigned*)ws;
  ushort*   h_ws = (ushort*)(ws + 524288);
  ushort*   wb   = (ushort*)(ws + 1048576);
  ushort*   xb   = (ushort*)(ws + 1048576 + 16777216);
  const bool xbf = ws_size >= (1048576ull + 16777216ull + 67108864ull);

  cvt_w<<<dim3(8192), dim3(256), 0, stream>>>(W[0],W[1],W[2],W[3],W[4],W[5],W[6],W[7], wb, bar);
  if (xbf) cvt_x<<<dim3(32768), dim3(256), 0, stream>>>(x, xb);

  if (xbf)
    lstm_persist<true ><<<dim3(256), dim3(256), 0, stream>>>(x, xb, wb, out, h_ws, bar);
  else
    lstm_persist<false><<<dim3(256), dim3(256), 0, stream>>>(x, xb, wb, out, h_ws, bar);
}